// Round 5
// baseline (78.554 us; speedup 1.0000x reference)
//
#include <hip/hip_runtime.h>

#define B_ 256
#define C_ 1000
#define D_ 512

typedef __bf16 bf16x4 __attribute__((ext_vector_type(4)));
typedef __bf16 bf16x8 __attribute__((ext_vector_type(8)));
typedef float  f32x4  __attribute__((ext_vector_type(4)));

__device__ __forceinline__ bf16x8 cvt8(float4 a, float4 b) {
    bf16x8 r;
    r[0] = (__bf16)a.x; r[1] = (__bf16)a.y; r[2] = (__bf16)a.z; r[3] = (__bf16)a.w;
    r[4] = (__bf16)b.x; r[5] = (__bf16)b.y; r[6] = (__bf16)b.z; r[7] = (__bf16)b.w;
    return r;
}
__device__ __forceinline__ bf16x4 cvt4(float4 a) {
    bf16x4 r;
    r[0] = (__bf16)a.x; r[1] = (__bf16)a.y; r[2] = (__bf16)a.z; r[3] = (__bf16)a.w;
    return r;
}

// Single fused kernel, no workspace.
// Per block: LDS-transpose one 16-row W tile (coalesced fp32 -> bf16 frags), then
// MFMA logits for 2 b-tiles/wave + Gram (A*A^T), x-norms accumulated in-loop,
// fused normalize + quadratic-form epilogue.
//   out[b,c] = ||l||^2 / sqrt(l^T G_c l),  l_s = (x_b . W_cs) * invx_b * invn_cs
// MFMA 16x16x32 D layout: n=lane&15 -> b, m=quad*4+reg -> (c_local=quad, s=reg).
// A/B operand layout: idx=lane&15, k=quad*8+j  (x loads land 16 lines/inst: coalesced).
__global__ __launch_bounds__(256, 2) void k_fused(const float* __restrict__ x,
                                                  const float* __restrict__ W,
                                                  float* __restrict__ out) {
    __shared__ __align__(16) char smem[64 * 272];
    int blk = blockIdx.x;
    int ct = blk >> 1;          // 0..249: c = 4*ct..4*ct+3
    int bh = blk & 1;           // b half
    int t = threadIdx.x;
    int lane = t & 63, wv = t >> 6;
    int l15 = lane & 15, quad = lane >> 4;

    // ---- prologue: W tile (16 rows x 512 fp32) -> LDS bf16 fragments ----
    // group g = ks*4+quad at byte g*272 (16 frags + 1 pad), frag l15 at +l15*16.
    const float* wbase = W + ct * 16 * D_;
    #pragma unroll
    for (int p = 0; p < 8; p++) {
        int ch = t + 256 * p;            // 2048 float4 chunks
        int row = ch >> 7, pos = ch & 127;
        float4 v = *(const float4*)(wbase + row * D_ + pos * 4);
        int ks = pos >> 3, qd = (pos >> 1) & 3, off = (pos & 1) * 4;
        *(bf16x4*)(smem + (ks * 4 + qd) * 272 + row * 16 + off * 2) = cvt4(v);
    }
    __syncthreads();

    int bt0 = bh * 8 + wv * 2;           // this wave's 2 b-tiles
    int bt1 = bt0 + 1;
    const float* xr0 = x + (bt0 * 16 + l15) * D_ + quad * 8;
    const float* xr1 = x + (bt1 * 16 + l15) * D_ + quad * 8;
    const char* lp = smem + quad * 272 + l15 * 16;

    f32x4 acc0 = {0.f, 0.f, 0.f, 0.f};
    f32x4 acc1 = {0.f, 0.f, 0.f, 0.f};
    f32x4 accg = {0.f, 0.f, 0.f, 0.f};
    float sn0 = 0.f, sn1 = 0.f;          // lane's quarter of ||x_b||^2
    #pragma unroll
    for (int ks = 0; ks < 16; ks++) {
        float4 a0 = *(const float4*)(xr0 + ks * 32);
        float4 c0 = *(const float4*)(xr0 + ks * 32 + 4);
        float4 a1 = *(const float4*)(xr1 + ks * 32);
        float4 c1 = *(const float4*)(xr1 + ks * 32 + 4);
        bf16x8 af = *(const bf16x8*)(lp + ks * 1088);
        bf16x8 b0 = cvt8(a0, c0);
        bf16x8 b1 = cvt8(a1, c1);
        sn0 += a0.x*a0.x + a0.y*a0.y + a0.z*a0.z + a0.w*a0.w
             + c0.x*c0.x + c0.y*c0.y + c0.z*c0.z + c0.w*c0.w;
        sn1 += a1.x*a1.x + a1.y*a1.y + a1.z*a1.z + a1.w*a1.w
             + c1.x*c1.x + c1.y*c1.y + c1.z*c1.z + c1.w*c1.w;
        acc0 = __builtin_amdgcn_mfma_f32_16x16x32_bf16(af, b0, acc0, 0, 0, 0);
        acc1 = __builtin_amdgcn_mfma_f32_16x16x32_bf16(af, b1, acc1, 0, 0, 0);
        accg = __builtin_amdgcn_mfma_f32_16x16x32_bf16(af, af, accg, 0, 0, 0);
    }

    // full ||x_b||^2: combine 4 quad-partners (same l15, same b)
    sn0 += __shfl_xor(sn0, 16); sn0 += __shfl_xor(sn0, 32);
    sn1 += __shfl_xor(sn1, 16); sn1 += __shfl_xor(sn1, 32);
    float ivx0 = 1.0f / fmaxf(sqrtf(sn0), 1e-12f);
    float ivx1 = 1.0f / fmaxf(sqrtf(sn1), 1e-12f);

    // lane's 4x4 Gram block: Gram[4q+s][4q+qq] is in lane 20*quad+qq, reg s
    float g[4][4];
    #pragma unroll
    for (int s = 0; s < 4; s++) {
        float v = accg[s];
        #pragma unroll
        for (int q = 0; q < 4; q++) g[s][q] = __shfl(v, 20 * quad + q);
    }
    float iv[4];
    #pragma unroll
    for (int s = 0; s < 4; s++) iv[s] = 1.0f / fmaxf(sqrtf(fmaxf(g[s][s], 0.f)), 1e-12f);

    #pragma unroll
    for (int sub = 0; sub < 2; sub++) {
        int bt = sub ? bt1 : bt0;
        f32x4 acc = sub ? acc1 : acc0;
        float ivx = sub ? ivx1 : ivx0;
        float l[4];
        #pragma unroll
        for (int s = 0; s < 4; s++) l[s] = acc[s] * ivx * iv[s];
        float num = l[0]*l[0] + l[1]*l[1] + l[2]*l[2] + l[3]*l[3];
        float den2 = 0.f;
        #pragma unroll
        for (int s = 0; s < 4; s++) {
            float r = 0.f;
            #pragma unroll
            for (int q = 0; q < 4; q++) r += g[s][q] * iv[q] * l[q];
            den2 += l[s] * iv[s] * r;
        }
        float den = fmaxf(sqrtf(fmaxf(den2, 0.f)), 1e-12f);
        float val = num / den;

        float4 o;   // pack c = ct*4..ct*4+3 for row b into one 16B store
        o.x = __shfl(val, l15);
        o.y = __shfl(val, l15 + 16);
        o.z = __shfl(val, l15 + 32);
        o.w = __shfl(val, l15 + 48);
        if (quad == 0)
            *(float4*)(out + (bt * 16 + l15) * C_ + ct * 4) = o;
    }
}

extern "C" void kernel_launch(void* const* d_in, const int* in_sizes, int n_in,
                              void* d_out, int out_size, void* d_ws, size_t ws_size,
                              hipStream_t stream) {
    const float* x = (const float*)d_in[0];   // [256,512] fp32
    const float* W = (const float*)d_in[1];   // [1000,4,512] fp32
    float* out = (float*)d_out;               // [256,1000] fp32
    k_fused<<<500, 256, 0, stream>>>(x, W, out);
}

// Round 6
// 70.864 us; speedup vs baseline: 1.1085x; 1.1085x over previous
//
#include <hip/hip_runtime.h>

#define B_ 256
#define C_ 1000
#define D_ 512

typedef __bf16 bf16x4 __attribute__((ext_vector_type(4)));
typedef __bf16 bf16x8 __attribute__((ext_vector_type(8)));
typedef float  f32x4  __attribute__((ext_vector_type(4)));

__device__ __forceinline__ bf16x4 cvt4(float4 a) {
    bf16x4 r;
    r[0] = (__bf16)a.x; r[1] = (__bf16)a.y; r[2] = (__bf16)a.z; r[3] = (__bf16)a.w;
    return r;
}

// Single kernel, single launch, no workspace.
// Block (ct, bh): W tile (16 rows = 4 c's) staged full-K to LDS bf16 frags;
// x half (128 rows = 8 b-tiles) staged in 4 K-chunks of 128 to LDS bf16 frags.
// Per wave: 2 b-tiles. 5 MFMAs/ks: logits x2, W-Gram (A*A^T), x-Gram x2 (B*B^T,
// diagonal = ||bf16 x_b||^2 -> invx, replacing the separate norm pass).
//   out[b,c] = ||l||^2 / sqrt(l^T G_c l),  l_s = (x_b.W_cs) * invx_b * invn_cs
// MFMA 16x16x32 D layout: n=lane&15, m=quad*4+reg. Frag layout in LDS: group
// stride 272 B (16 frags + 16B pad), frag l15 at +l15*16 -> ds_read_b128.
__global__ __launch_bounds__(256, 3) void k_fused(const float* __restrict__ x,
                                                  const float* __restrict__ W,
                                                  float* __restrict__ out) {
    __shared__ __align__(16) char smW[64 * 272];    // groups ks*4+qd, ks=0..15
    __shared__ __align__(16) char smX[128 * 272];   // groups (bt*4+ksl)*4+qd
    int blk = blockIdx.x;
    int ct = blk >> 1;          // 0..249: c = 4*ct..4*ct+3
    int bh = blk & 1;           // b half (128 rows)
    int t = threadIdx.x;
    int lane = t & 63, wv = t >> 6;
    int l15 = lane & 15, quad = lane >> 4;

    // ---- W tile (16 rows x 512 fp32, coalesced) -> LDS bf16 frags, full K ----
    const float* wbase = W + ct * 16 * D_;
    #pragma unroll
    for (int p = 0; p < 8; p++) {
        int ch = t + 256 * p;            // 2048 float4 chunks
        int row = ch >> 7, pos = ch & 127;
        float4 v = *(const float4*)(wbase + row * D_ + pos * 4);
        int ks = pos >> 3, qd = (pos >> 1) & 3, off = (pos & 1) * 4;
        *(bf16x4*)(smW + (ks * 4 + qd) * 272 + row * 16 + off * 2) = cvt4(v);
    }

    int bt0 = wv * 2, bt1 = bt0 + 1;     // local b-tiles (of 8 in this half)
    const char* lpw  = smW + quad * 272 + l15 * 16;
    const char* lpx0 = smX + (bt0 * 16 + quad) * 272 + l15 * 16;
    const char* lpx1 = smX + (bt1 * 16 + quad) * 272 + l15 * 16;
    const float* xbase = x + bh * 128 * D_;

    f32x4 acc0  = {0.f, 0.f, 0.f, 0.f};
    f32x4 acc1  = {0.f, 0.f, 0.f, 0.f};
    f32x4 accg  = {0.f, 0.f, 0.f, 0.f};
    f32x4 accx0 = {0.f, 0.f, 0.f, 0.f};
    f32x4 accx1 = {0.f, 0.f, 0.f, 0.f};

    for (int kc = 0; kc < 4; kc++) {
        __syncthreads();                 // guard smX reuse (and W stage on kc=0 path below)
        // ---- stage x chunk: 128 rows x 128 k (coalesced fp32) -> LDS frags ----
        #pragma unroll
        for (int p = 0; p < 16; p++) {
            int id = t + 256 * p;        // 4096 float4 chunks
            int row = id >> 5, col = id & 31;
            float4 v = *(const float4*)(xbase + row * D_ + kc * 128 + col * 4);
            int ksl = col >> 3, qd = (col >> 1) & 3, off = (col & 1) * 4;
            *(bf16x4*)(smX + ((row >> 4) * 16 + ksl * 4 + qd) * 272
                           + (row & 15) * 16 + off * 2) = cvt4(v);
        }
        __syncthreads();
        #pragma unroll
        for (int ksl = 0; ksl < 4; ksl++) {
            bf16x8 af = *(const bf16x8*)(lpw + (kc * 4 + ksl) * 1088);
            bf16x8 b0 = *(const bf16x8*)(lpx0 + ksl * 1088);
            bf16x8 b1 = *(const bf16x8*)(lpx1 + ksl * 1088);
            acc0  = __builtin_amdgcn_mfma_f32_16x16x32_bf16(af, b0, acc0, 0, 0, 0);
            acc1  = __builtin_amdgcn_mfma_f32_16x16x32_bf16(af, b1, acc1, 0, 0, 0);
            accg  = __builtin_amdgcn_mfma_f32_16x16x32_bf16(af, af, accg, 0, 0, 0);
            accx0 = __builtin_amdgcn_mfma_f32_16x16x32_bf16(b0, b0, accx0, 0, 0, 0);
            accx1 = __builtin_amdgcn_mfma_f32_16x16x32_bf16(b1, b1, accx1, 0, 0, 0);
        }
    }

    // ---- W Gram 4x4 block: Gram[4q+s][4q+qq] is in lane 20*quad+qq, reg s ----
    float g[4][4];
    #pragma unroll
    for (int s = 0; s < 4; s++) {
        float v = accg[s];
        #pragma unroll
        for (int q = 0; q < 4; q++) g[s][q] = __shfl(v, 20 * quad + q);
    }
    float iv[4];
    #pragma unroll
    for (int s = 0; s < 4; s++) iv[s] = 1.0f / fmaxf(sqrtf(fmaxf(g[s][s], 0.f)), 1e-12f);

    // ---- x norms from x-Gram diagonal: D[l15][l15] lives in lane ((l15>>2)<<4)|l15, reg l15&3 ----
    int r3 = l15 & 3;
    int srcl = ((l15 >> 2) << 4) | l15;
    float p0 = (r3 == 0) ? accx0[0] : (r3 == 1) ? accx0[1] : (r3 == 2) ? accx0[2] : accx0[3];
    float p1 = (r3 == 0) ? accx1[0] : (r3 == 1) ? accx1[1] : (r3 == 2) ? accx1[2] : accx1[3];
    float d0 = __shfl(p0, srcl);
    float d1 = __shfl(p1, srcl);
    float ivx0 = 1.0f / fmaxf(sqrtf(fmaxf(d0, 0.f)), 1e-12f);
    float ivx1 = 1.0f / fmaxf(sqrtf(fmaxf(d1, 0.f)), 1e-12f);

    #pragma unroll
    for (int sub = 0; sub < 2; sub++) {
        f32x4 acc = sub ? acc1 : acc0;
        float ivx = sub ? ivx1 : ivx0;
        int bt = bh * 8 + wv * 2 + sub;  // global b-tile
        float l[4];
        #pragma unroll
        for (int s = 0; s < 4; s++) l[s] = acc[s] * ivx * iv[s];
        float num = l[0]*l[0] + l[1]*l[1] + l[2]*l[2] + l[3]*l[3];
        float den2 = 0.f;
        #pragma unroll
        for (int s = 0; s < 4; s++) {
            float r = 0.f;
            #pragma unroll
            for (int q = 0; q < 4; q++) r += g[s][q] * iv[q] * l[q];
            den2 += l[s] * iv[s] * r;
        }
        float den = fmaxf(sqrtf(fmaxf(den2, 0.f)), 1e-12f);
        float val = num / den;

        float4 o;   // pack c = ct*4..ct*4+3 for row b into one 16B store
        o.x = __shfl(val, l15);
        o.y = __shfl(val, l15 + 16);
        o.z = __shfl(val, l15 + 32);
        o.w = __shfl(val, l15 + 48);
        if (quad == 0)
            *(float4*)(out + (bt * 16 + l15) * C_ + ct * 4) = o;
    }
}

extern "C" void kernel_launch(void* const* d_in, const int* in_sizes, int n_in,
                              void* d_out, int out_size, void* d_ws, size_t ws_size,
                              hipStream_t stream) {
    const float* x = (const float*)d_in[0];   // [256,512] fp32
    const float* W = (const float*)d_in[1];   // [1000,4,512] fp32
    float* out = (float*)d_out;               // [256,1000] fp32
    k_fused<<<500, 256, 0, stream>>>(x, W, out);
}

// Round 7
// 69.162 us; speedup vs baseline: 1.1358x; 1.0246x over previous
//
#include <hip/hip_runtime.h>

#define B_ 256
#define C_ 1000
#define D_ 512

typedef __bf16 bf16x4 __attribute__((ext_vector_type(4)));
typedef __bf16 bf16x8 __attribute__((ext_vector_type(8)));
typedef float  f32x4  __attribute__((ext_vector_type(4)));

__device__ __forceinline__ bf16x8 cvt8(float4 a, float4 b) {
    bf16x8 r;
    r[0] = (__bf16)a.x; r[1] = (__bf16)a.y; r[2] = (__bf16)a.z; r[3] = (__bf16)a.w;
    r[4] = (__bf16)b.x; r[5] = (__bf16)b.y; r[6] = (__bf16)b.z; r[7] = (__bf16)b.w;
    return r;
}
__device__ __forceinline__ bf16x4 cvt4(float4 a) {
    bf16x4 r;
    r[0] = (__bf16)a.x; r[1] = (__bf16)a.y; r[2] = (__bf16)a.z; r[3] = (__bf16)a.w;
    return r;
}

// Pack x (512 KB fp32) -> bf16 MFMA-fragment layout [bt][ks][quad][l15][8] + fp32 invx[b].
__global__ __launch_bounds__(256) void k_packx(const float* __restrict__ x,
                                               __bf16* __restrict__ xf,
                                               float* __restrict__ invx) {
    int n = blockIdx.x * 256 + threadIdx.x;   // 16384 chunks of 8 elems
    int r = n >> 6;                           // x row (wave-uniform)
    int j = n & 63;
    const float* src = x + r * D_ + j * 8;
    float4 a = *(const float4*)src;
    float4 b = *(const float4*)(src + 4);
    int bt = r >> 4, l15 = r & 15, ks = j >> 2, quad = j & 3;
    int idx = ((bt * 16 + ks) * 4 + quad) * 16 + l15;
    *(bf16x8*)(xf + idx * 8) = cvt8(a, b);
    float sn = a.x*a.x + a.y*a.y + a.z*a.z + a.w*a.w
             + b.x*b.x + b.y*b.y + b.z*b.z + b.w*b.w;
    #pragma unroll
    for (int o = 32; o; o >>= 1) sn += __shfl_down(sn, o);
    if ((threadIdx.x & 63) == 0) invx[r] = 1.0f / fmaxf(sqrtf(sn), 1e-12f);
}

// Main: 250 blocks (~1/CU). Block = (ct2 = 32 W rows = 8 c's, bh = 128 b rows).
// LDS-transpose the 32-row W tile (2 fragment tiles); per wave a 2x2 (c-tile x
// b-tile) MFMA grid + per-tile Gram; fused normalize + quadratic-form epilogue.
// MFMA 16x16x32 D layout: n=lane&15 -> b, m=quad*4+reg -> (c_local=quad, s=reg).
__global__ __launch_bounds__(256, 2) void k_main(const float* __restrict__ W,
                                                 const __bf16* __restrict__ xf,
                                                 const float* __restrict__ invx,
                                                 float* __restrict__ out) {
    __shared__ __align__(16) char smW[2 * 64 * 272];   // 2 tiles x 64 groups x 272B
    int blk = blockIdx.x;
    int ct2 = blk >> 1;          // 0..124: c = 8*ct2 .. 8*ct2+7
    int bh = blk & 1;            // b half
    int t = threadIdx.x;
    int lane = t & 63, wv = t >> 6;
    int l15 = lane & 15, quad = lane >> 4;

    // ---- W tile (32 rows x 512 fp32, coalesced) -> LDS bf16 fragments ----
    const float* wbase = W + ct2 * 32 * D_;
    #pragma unroll
    for (int p = 0; p < 16; p++) {
        int ch = t + 256 * p;            // 4096 float4 chunks
        int row = ch >> 7, pos = ch & 127;
        float4 v = *(const float4*)(wbase + row * D_ + pos * 4);
        int ks = pos >> 3, qd = (pos >> 1) & 3, off = (pos & 1) * 4;
        *(bf16x4*)(smW + (row >> 4) * 17408 + (ks * 4 + qd) * 272
                       + (row & 15) * 16 + off * 2) = cvt4(v);
    }
    __syncthreads();

    int bt0 = bh * 8 + wv * 2, bt1 = bt0 + 1;   // global b-tiles
    const bf16x8* xp0 = (const bf16x8*)xf + (bt0 * 64 + quad) * 16 + l15;
    const bf16x8* xp1 = (const bf16x8*)xf + (bt1 * 64 + quad) * 16 + l15;
    const char* lp0 = smW + quad * 272 + l15 * 16;
    const char* lp1 = lp0 + 17408;

    f32x4 acc00 = {0.f,0.f,0.f,0.f}, acc01 = {0.f,0.f,0.f,0.f};
    f32x4 acc10 = {0.f,0.f,0.f,0.f}, acc11 = {0.f,0.f,0.f,0.f};
    f32x4 accg0 = {0.f,0.f,0.f,0.f}, accg1 = {0.f,0.f,0.f,0.f};
    #pragma unroll
    for (int ks = 0; ks < 16; ks++) {
        bf16x8 a0 = *(const bf16x8*)(lp0 + ks * 1088);
        bf16x8 a1 = *(const bf16x8*)(lp1 + ks * 1088);
        bf16x8 b0 = xp0[ks * 64];
        bf16x8 b1 = xp1[ks * 64];
        acc00 = __builtin_amdgcn_mfma_f32_16x16x32_bf16(a0, b0, acc00, 0, 0, 0);
        acc01 = __builtin_amdgcn_mfma_f32_16x16x32_bf16(a0, b1, acc01, 0, 0, 0);
        acc10 = __builtin_amdgcn_mfma_f32_16x16x32_bf16(a1, b0, acc10, 0, 0, 0);
        acc11 = __builtin_amdgcn_mfma_f32_16x16x32_bf16(a1, b1, acc11, 0, 0, 0);
        accg0 = __builtin_amdgcn_mfma_f32_16x16x32_bf16(a0, a0, accg0, 0, 0, 0);
        accg1 = __builtin_amdgcn_mfma_f32_16x16x32_bf16(a1, a1, accg1, 0, 0, 0);
    }

    float ivx0 = invx[bt0 * 16 + l15];
    float ivx1 = invx[bt1 * 16 + l15];

    #pragma unroll
    for (int u = 0; u < 2; u++) {
        f32x4 accg = u ? accg1 : accg0;
        // lane's 4x4 Gram block of this 16-row tile: Gram[4q+s][4q+qq] in lane 20*quad+qq, reg s
        float g[4][4];
        #pragma unroll
        for (int s = 0; s < 4; s++) {
            float v = accg[s];
            #pragma unroll
            for (int q = 0; q < 4; q++) g[s][q] = __shfl(v, 20 * quad + q);
        }
        float iv[4];
        #pragma unroll
        for (int s = 0; s < 4; s++) iv[s] = 1.0f / fmaxf(sqrtf(fmaxf(g[s][s], 0.f)), 1e-12f);

        #pragma unroll
        for (int sub = 0; sub < 2; sub++) {
            f32x4 acc = u ? (sub ? acc11 : acc10) : (sub ? acc01 : acc00);
            float ivx = sub ? ivx1 : ivx0;
            int bt = sub ? bt1 : bt0;
            float l[4];
            #pragma unroll
            for (int s = 0; s < 4; s++) l[s] = acc[s] * ivx * iv[s];
            float num = l[0]*l[0] + l[1]*l[1] + l[2]*l[2] + l[3]*l[3];
            float den2 = 0.f;
            #pragma unroll
            for (int s = 0; s < 4; s++) {
                float r = 0.f;
                #pragma unroll
                for (int q = 0; q < 4; q++) r += g[s][q] * iv[q] * l[q];
                den2 += l[s] * iv[s] * r;
            }
            float den = fmaxf(sqrtf(fmaxf(den2, 0.f)), 1e-12f);
            float val = num / den;

            float4 o;   // pack c = ct2*8 + u*4 .. +3 for row b
            o.x = __shfl(val, l15);
            o.y = __shfl(val, l15 + 16);
            o.z = __shfl(val, l15 + 32);
            o.w = __shfl(val, l15 + 48);
            if (quad == 0)
                *(float4*)(out + (bt * 16 + l15) * C_ + ct2 * 8 + u * 4) = o;
        }
    }
}

extern "C" void kernel_launch(void* const* d_in, const int* in_sizes, int n_in,
                              void* d_out, int out_size, void* d_ws, size_t ws_size,
                              hipStream_t stream) {
    const float* x = (const float*)d_in[0];   // [256,512] fp32
    const float* W = (const float*)d_in[1];   // [1000,4,512] fp32
    float* out = (float*)d_out;               // [256,1000] fp32

    char* ws = (char*)d_ws;
    __bf16* xf  = (__bf16*)ws;                // 524,288 B
    float*  ivx = (float*)(ws + 524288);      // 1,024 B

    k_packx<<<64, 256, 0, stream>>>(x, xf, ivx);
    k_main<<<250, 256, 0, stream>>>(W, xf, ivx, out);
}